// Round 1
// baseline (218.677 us; speedup 1.0000x reference)
//
#include <hip/hip_runtime.h>
#include <math.h>

#define NPROP 4
#define SFULL 72
#define FH 11
#define FW 20
#define CF 64
#define CB 512
#define FDIM 704   // CF*FH
#define HW 220     // FH*FW
#define CHT 32
#define NTILE 16   // CB/CHT
#define MTOT 153   // 75 (Y1) + 75 (Y2) + 3 (att scores)

// ---------------- Kernel 1: geometry + gathered 1x1 conv ----------------
// grid = B blocks, 512 threads. Each block streams feat[b] once (coalesced,
// LDS-staged, register double-buffered) and computes anchor_feat[b,p,c*11+y]
// = sum_ch feat[b,ch,y,cut_x[p,y]] * conv_w[c,ch] + conv_b[c] (0 if invalid).
__global__ __launch_bounds__(512) void k_gconv(
    const float* __restrict__ feat, const float* __restrict__ rpn,
    const float* __restrict__ conv_w, const float* __restrict__ conv_b,
    float* __restrict__ af, float* __restrict__ xs_full, float* __restrict__ out)
{
  __shared__ __align__(16) float lds_f[CHT * HW];   // 7040 floats
  __shared__ __align__(16) float lds_w[CHT * 68];   // [ch][c] padded to 68
  __shared__ float sh_sx[NPROP], sh_sy[NPROP], sh_it[NPROP];
  __shared__ int   sh_pos[44];

  const int b = blockIdx.x;
  const int t = threadIdx.x;

  // --- per-proposal geometry ---
  if (t < NPROP) {
    const float* rp = rpn + (b * NPROP + t) * 4;
    float sx = rp[0] * (1.0f / 640.0f);
    float sy = rp[1] * (1.0f / 360.0f);
    float tn = tanf(rp[3] * 0.017453292519943295f);
    sh_sx[t] = sx; sh_sy[t] = sy; sh_it[t] = 1.0f / tn;
    out[(b * NPROP + t) * 77 + 2] = 1.0f - sy;
    out[(b * NPROP + t) * 77 + 3] = sx;
  }
  __syncthreads();
  // xs_full (72 offsets per proposal)
  if (t < NPROP * SFULL) {
    int p = t / SFULL, i = t - p * SFULL;
    float ay = 1.0f - (float)i * (1.0f / 71.0f);
    xs_full[(b * NPROP + p) * SFULL + i] =
        (sh_sx[p] + (sh_sy[p] - ay) * sh_it[p]) * 640.0f;
  }
  // cut indices (flipped along fmap_h; invalid rule: u<0 || u>FW)
  if (t < NPROP * FH) {
    int p = t / FH, y = t - p * FH;
    float acy = 1.0f - (float)(10 - y) * 0.1f;   // linspace(1,0,11)[10-y]
    float xc = (sh_sx[p] + (sh_sy[p] - acy) * sh_it[p]) * 640.0f;
    float u = rintf(xc * (1.0f / 32.0f));        // round half-to-even
    int ui = (int)u;
    int cut = min(max(ui, 0), FW - 1);
    bool inv = (ui < 0) | (ui > FW);
    sh_pos[t] = inv ? -1 : (y * FW + cut);
  }
  __syncthreads();

  // thread -> (4 output channels, up to 2 slots)
  const int c4 = (t & 15) * 4;
  const int sb = t >> 4;            // 0..31
  const int s0 = sb;
  const int s1 = sb + 32;
  const bool has1 = (s1 < 44);      // wave-uniform (sb spans 4 values/wave)
  const int pos0 = sh_pos[s0];
  const int pos1 = has1 ? sh_pos[s1] : -1;
  const int rp0 = pos0 < 0 ? 0 : pos0;
  const int rp1 = pos1 < 0 ? 0 : pos1;

  const float* fb = feat + (size_t)b * (CB * HW);

  float4 pf[4];
  float  pw[4];
  // prefetch tile 0
  {
    const float4* g = (const float4*)fb;
    #pragma unroll
    for (int k = 0; k < 4; k++) { int i = t + 512 * k; if (i < 1760) pf[k] = g[i]; }
    #pragma unroll
    for (int k = 0; k < 4; k++) { int e = t + 512 * k; int ch = e & 31, c = e >> 5;
                                  pw[k] = conv_w[c * CB + ch]; }
  }
  #pragma unroll
  for (int k = 0; k < 4; k++) { int i = t + 512 * k; if (i < 1760) ((float4*)lds_f)[i] = pf[k]; }
  #pragma unroll
  for (int k = 0; k < 4; k++) { int e = t + 512 * k; int ch = e & 31, c = e >> 5;
                                lds_w[ch * 68 + c] = pw[k]; }
  __syncthreads();

  float4 a0 = {0.f, 0.f, 0.f, 0.f}, a1 = {0.f, 0.f, 0.f, 0.f};

  for (int ct = 0; ct < NTILE; ++ct) {
    // issue next-tile global loads (overlap with compute below)
    if (ct + 1 < NTILE) {
      const float4* g = (const float4*)(fb + (ct + 1) * CHT * HW);
      #pragma unroll
      for (int k = 0; k < 4; k++) { int i = t + 512 * k; if (i < 1760) pf[k] = g[i]; }
      const int chb = (ct + 1) * CHT;
      #pragma unroll
      for (int k = 0; k < 4; k++) { int e = t + 512 * k; int ch = e & 31, c = e >> 5;
                                    pw[k] = conv_w[c * CB + chb + ch]; }
    }
    // compute current tile
    #pragma unroll 8
    for (int ch = 0; ch < CHT; ++ch) {
      float4 w = *(const float4*)&lds_w[ch * 68 + c4];
      float f0 = lds_f[ch * HW + rp0];
      a0.x += w.x * f0; a0.y += w.y * f0; a0.z += w.z * f0; a0.w += w.w * f0;
      if (has1) {
        float f1 = lds_f[ch * HW + rp1];
        a1.x += w.x * f1; a1.y += w.y * f1; a1.z += w.z * f1; a1.w += w.w * f1;
      }
    }
    __syncthreads();
    if (ct + 1 < NTILE) {
      #pragma unroll
      for (int k = 0; k < 4; k++) { int i = t + 512 * k; if (i < 1760) ((float4*)lds_f)[i] = pf[k]; }
      #pragma unroll
      for (int k = 0; k < 4; k++) { int e = t + 512 * k; int ch = e & 31, c = e >> 5;
                                    lds_w[ch * 68 + c] = pw[k]; }
      __syncthreads();
    }
  }

  // write anchor_feat (af[b,p, c*11+y]); invalid -> 0
  {
    int p = s0 / FH, y = s0 - p * FH;
    float* dst = af + ((size_t)(b * NPROP + p)) * FDIM + y;
    #pragma unroll
    for (int cc = 0; cc < 4; ++cc) {
      float v = (pos0 < 0) ? 0.0f : (((float*)&a0)[cc] + conv_b[c4 + cc]);
      dst[(c4 + cc) * FH] = v;
    }
    if (has1) {
      int p1 = s1 / FH, y1 = s1 - p1 * FH;
      float* dst1 = af + ((size_t)(b * NPROP + p1)) * FDIM + y1;
      #pragma unroll
      for (int cc = 0; cc < 4; ++cc) {
        float v = (pos1 < 0) ? 0.0f : (((float*)&a1)[cc] + conv_b[c4 + cc]);
        dst1[(c4 + cc) * FH] = v;
      }
    }
  }
}

// ---------------- Kernel 2: attention + heads + assembly ----------------
// Uses cat@W = att_feat@W1 + anchor_feat@W2 with att_feat = att_mat @ af,
// so the 1408-dots become 2x 704-dots computed BEFORE the 4x4 mixing:
// Y[p][m]: m in [0,75) = af[p].W1_row(m), [75,150) = af[p].W2_row(m-75),
// [150,153) = af[p].att_w[m-150].  Then out = mix + bias + xs_full.
__global__ __launch_bounds__(256) void k_head(
    const float* __restrict__ af, const float* __restrict__ xs_full,
    const float* __restrict__ att_w, const float* __restrict__ att_b,
    const float* __restrict__ cls_w, const float* __restrict__ cls_b,
    const float* __restrict__ reg_w, const float* __restrict__ reg_b,
    float* __restrict__ out)
{
  __shared__ __align__(16) float af_s[NPROP * FDIM];  // 2816
  __shared__ float wt[64 * MTOT];                     // [j][m], stride 153 (odd)
  __shared__ float Y[NPROP * MTOT];                   // 612
  __shared__ float Amat[NPROP][NPROP];

  const int b = blockIdx.x, t = threadIdx.x;

  {
    const float4* src = (const float4*)(af + (size_t)b * NPROP * FDIM);
    for (int i = t; i < NPROP * FDIM / 4; i += 256) ((float4*)af_s)[i] = src[i];
  }
  __syncthreads();

  const int d0 = t, d1 = t + 256, d2 = t + 512;
  const int p0 = d0 / MTOT, m0 = d0 % MTOT;
  const int p1 = d1 / MTOT, m1 = d1 % MTOT;
  const int p2 = d2 / MTOT, m2 = d2 % MTOT;
  const bool h2 = (d2 < NPROP * MTOT);
  float acc0 = 0.f, acc1 = 0.f, acc2 = 0.f;

  const int j = t & 63;
  const int mb = t >> 6;

  for (int jt = 0; jt < FDIM / 64; ++jt) {
    // stage weight tile wt[j][m] = vrow_m[jt*64 + j] (coalesced in j)
    for (int m = mb; m < MTOT; m += 4) {
      const float* rowp;
      if (m < 150) {
        int o = (m < 75) ? m : m - 75;
        int half = (m < 75) ? 0 : 704;
        rowp = ((o < 2) ? (cls_w + o * 1408) : (reg_w + (o - 2) * 1408)) + half;
      } else {
        rowp = att_w + (m - 150) * FDIM;
      }
      wt[j * MTOT + m] = rowp[jt * 64 + j];
    }
    __syncthreads();
    const int jb = jt * 64;
    #pragma unroll 4
    for (int jj = 0; jj < 64; ++jj) {
      float a0v = af_s[p0 * FDIM + jb + jj];
      float a1v = af_s[p1 * FDIM + jb + jj];
      acc0 += a0v * wt[jj * MTOT + m0];
      acc1 += a1v * wt[jj * MTOT + m1];
      if (h2) acc2 += af_s[p2 * FDIM + jb + jj] * wt[jj * MTOT + m2];
    }
    __syncthreads();
  }
  Y[d0] = acc0; Y[d1] = acc1; if (h2) Y[d2] = acc2;
  __syncthreads();

  // softmax over 3 non-self anchors -> scattered off-diagonal 4x4
  if (t < NPROP) {
    float s0 = Y[t * MTOT + 150] + att_b[0];
    float s1 = Y[t * MTOT + 151] + att_b[1];
    float s2 = Y[t * MTOT + 152] + att_b[2];
    float mx = fmaxf(s0, fmaxf(s1, s2));
    float e0 = expf(s0 - mx), e1 = expf(s1 - mx), e2 = expf(s2 - mx);
    float inv = 1.0f / (e0 + e1 + e2);
    float a[3] = {e0 * inv, e1 * inv, e2 * inv};
    #pragma unroll
    for (int q = 0; q < NPROP; q++)
      Amat[t][q] = (q == t) ? 0.0f : a[(q < t) ? q : q - 1];
  }
  __syncthreads();

  // out[p][o]: o<2 cls (cols 0,1), o==2 reg0 (col 4), o>=3 reg(o-2) + xs (col o+2)
  for (int d = t; d < NPROP * 75; d += 256) {
    int p = d / 75, o = d - p * 75;
    float v = Y[p * MTOT + 75 + o];
    #pragma unroll
    for (int q = 0; q < NPROP; q++) v += Amat[p][q] * Y[q * MTOT + o];
    v += (o < 2) ? cls_b[o] : reg_b[o - 2];
    int col = (o < 2) ? o : o + 2;
    if (o >= 3) v += xs_full[(b * NPROP + p) * SFULL + (o - 3)];
    out[(b * NPROP + p) * 77 + col] = v;
  }
}

extern "C" void kernel_launch(void* const* d_in, const int* in_sizes, int n_in,
                              void* d_out, int out_size, void* d_ws, size_t ws_size,
                              hipStream_t stream) {
  const float* feat   = (const float*)d_in[0];
  const float* rpn    = (const float*)d_in[1];
  const float* conv_w = (const float*)d_in[2];
  const float* conv_b = (const float*)d_in[3];
  const float* att_w  = (const float*)d_in[4];
  const float* att_b  = (const float*)d_in[5];
  const float* cls_w  = (const float*)d_in[6];
  const float* cls_b  = (const float*)d_in[7];
  const float* reg_w  = (const float*)d_in[8];
  const float* reg_b  = (const float*)d_in[9];
  float* out = (float*)d_out;

  float* af = (float*)d_ws;                       // 512*4*704 floats
  float* xs = af + (size_t)512 * NPROP * FDIM;    // 512*4*72 floats

  k_gconv<<<512, 512, 0, stream>>>(feat, rpn, conv_w, conv_b, af, xs, out);
  k_head<<<512, 256, 0, stream>>>(af, xs, att_w, att_b, cls_w, cls_b,
                                  reg_w, reg_b, out);
}

// Round 2
// 114.484 us; speedup vs baseline: 1.9101x; 1.9101x over previous
//
#include <hip/hip_runtime.h>
#include <math.h>

#define NPROP 4
#define SFULL 72
#define FH 11
#define FW 20
#define CF 64
#define CB 512
#define FDIM 704   // CF*FH
#define HW 220     // FH*FW
#define CHT 32
#define NTILE 16   // CB/CHT
#define MROWS 160  // padded head-output rows (153 used)

typedef __attribute__((ext_vector_type(8))) short bf16x8;
typedef __attribute__((ext_vector_type(4))) float f32x4;

__device__ __forceinline__ unsigned short f2bf(float x) {
  unsigned u = __float_as_uint(x);
  u += 0x7FFFu + ((u >> 16) & 1u);
  return (unsigned short)(u >> 16);
}

// ---------------- w_prep: permute head weights to f' = y*64+c ordering ----
// Wc[m][f'] bf16, m in [0,160): 0..74 = W1 rows (cls0,cls1,reg0..72),
// 75..149 = W2 rows, 150..152 = att rows, 153..159 = zero pad.
__global__ void w_prep(const float* __restrict__ cls_w, const float* __restrict__ reg_w,
                       const float* __restrict__ att_w, unsigned short* __restrict__ Wc) {
  const int m = blockIdx.x;
  const int t = threadIdx.x;
  const float* rowp = nullptr;
  if (m < 150) {
    int o = (m < 75) ? m : m - 75;
    int half = (m < 75) ? 0 : FDIM;
    rowp = ((o < 2) ? (cls_w + o * 2 * FDIM) : (reg_w + (o - 2) * 2 * FDIM)) + half;
  } else if (m < 153) {
    rowp = att_w + (m - 150) * FDIM;
  }
  for (int f = t; f < FDIM; f += 256) {
    float v = rowp ? rowp[f] : 0.0f;
    int fp = (f % FH) * 64 + (f / FH);   // f = c*11+y -> f' = y*64+c
    Wc[m * FDIM + fp] = f2bf(v);
  }
}

// ---------------- Kernel 1: geometry + gathered 1x1 conv via MFMA ---------
// grid = 512 blocks (one batch), 512 threads (8 waves).
// Streams feat[b] once through LDS; gathers the 44 needed columns into a
// bf16 A-tile; MFMA 16x16x32 accumulates A[48x512] x W^T[512x64].
// Wave w: ntile = w&3 (16 couts), mhalf = w>>2 (mt {0,1} or {2}).
__global__ __launch_bounds__(512) void k_gconv(
    const float* __restrict__ feat, const float* __restrict__ rpn,
    const float* __restrict__ conv_w, const float* __restrict__ conv_b,
    unsigned short* __restrict__ af, float* __restrict__ xs_full,
    float* __restrict__ out)
{
  __shared__ __align__(16) float lds_f[CHT * HW];       // 28160 B
  __shared__ __align__(16) unsigned A_lds[2][48 * 20];  // bf16 [48][40], dbuf
  __shared__ float sh_sx[NPROP], sh_sy[NPROP], sh_it[NPROP];
  __shared__ int   sh_pos[48];

  const int b = blockIdx.x;
  const int t = threadIdx.x;
  const int l = t & 63;
  const int wid = t >> 6;
  const int nt = wid & 3;
  const int mhalf = wid >> 2;

  // --- per-proposal geometry ---
  if (t < NPROP) {
    const float* rp = rpn + (b * NPROP + t) * 4;
    float sx = rp[0] * (1.0f / 640.0f);
    float sy = rp[1] * (1.0f / 360.0f);
    float tn = tanf(rp[3] * 0.017453292519943295f);
    sh_sx[t] = sx; sh_sy[t] = sy; sh_it[t] = 1.0f / tn;
    out[(b * NPROP + t) * 77 + 2] = 1.0f - sy;
    out[(b * NPROP + t) * 77 + 3] = sx;
  }
  __syncthreads();
  if (t < NPROP * SFULL) {
    int p = t / SFULL, i = t - p * SFULL;
    float ay = 1.0f - (float)i * (1.0f / 71.0f);
    xs_full[(b * NPROP + p) * SFULL + i] =
        (sh_sx[p] + (sh_sy[p] - ay) * sh_it[p]) * 640.0f;
  }
  if (t < 48) {
    int ps = -1;
    if (t < NPROP * FH) {
      int p = t / FH, y = t - p * FH;
      float acy = 1.0f - (float)(10 - y) * 0.1f;
      float xc = (sh_sx[p] + (sh_sy[p] - acy) * sh_it[p]) * 640.0f;
      int ui = (int)rintf(xc * (1.0f / 32.0f));
      int cut = min(max(ui, 0), FW - 1);
      ps = ((ui < 0) | (ui > FW)) ? -1 : (y * FW + cut);
    }
    sh_pos[t] = ps;
  }

  const float* fb = feat + (size_t)b * (CB * HW);
  float4 pf[4];
  float  bw[8];

#define LOADF(ct) { const float4* g = (const float4*)(fb + (ct) * CHT * HW); \
    _Pragma("unroll") for (int k = 0; k < 4; k++) { int i = t + 512 * k; if (i < 1760) pf[k] = g[i]; } }
#define STOREF() { _Pragma("unroll") for (int k = 0; k < 4; k++) { int i = t + 512 * k; if (i < 1760) ((float4*)lds_f)[i] = pf[k]; } }
#define LOADB(ct) { const float* wp = conv_w + (16 * nt + (l & 15)) * CB + (ct) * CHT + (l >> 4) * 8; \
    float4 u = *(const float4*)wp; float4 v = *(const float4*)(wp + 4); \
    bw[0] = u.x; bw[1] = u.y; bw[2] = u.z; bw[3] = u.w; bw[4] = v.x; bw[5] = v.y; bw[6] = v.z; bw[7] = v.w; }

  LOADF(0);
  LOADB(0);
  STOREF();
  __syncthreads();   // lds_f(0) ready; sh_pos visible

  f32x4 acc0 = {0.f, 0.f, 0.f, 0.f}, acc1 = {0.f, 0.f, 0.f, 0.f};

  for (int ct = 0; ct < NTILE; ++ct) {
    if (ct + 1 < NTILE) LOADF(ct + 1);
    // gather tile ct -> A_lds[ct&1]  (48 slots x 16 kk-pairs = 768 entries)
    {
      int buf = ct & 1;
      #pragma unroll
      for (int e = t; e < 768; e += 512) {
        int s = e >> 4, kp = e & 15;
        int pos = sh_pos[s];
        int pp = pos < 0 ? 0 : pos;
        float lo = lds_f[(2 * kp) * HW + pp];
        float hi = lds_f[(2 * kp + 1) * HW + pp];
        unsigned pk = (pos < 0) ? 0u
          : ((unsigned)f2bf(lo) | ((unsigned)f2bf(hi) << 16));
        A_lds[buf][s * 20 + kp] = pk;
      }
    }
    // convert current weights to bf16 fragment
    bf16x8 bfr;
    #pragma unroll
    for (int j = 0; j < 8; j++) bfr[j] = (short)f2bf(bw[j]);
    if (ct + 1 < NTILE) LOADB(ct + 1);
    __syncthreads();   // A ready; lds_f free
    {
      const unsigned short* Ab = (const unsigned short*)A_lds[ct & 1];
      if (mhalf == 0) {
        bf16x8 a0 = *(const bf16x8*)(Ab + (0 + (l & 15)) * 40 + (l >> 4) * 8);
        bf16x8 a1 = *(const bf16x8*)(Ab + (16 + (l & 15)) * 40 + (l >> 4) * 8);
        acc0 = __builtin_amdgcn_mfma_f32_16x16x32_bf16(a0, bfr, acc0, 0, 0, 0);
        acc1 = __builtin_amdgcn_mfma_f32_16x16x32_bf16(a1, bfr, acc1, 0, 0, 0);
      } else {
        bf16x8 a2 = *(const bf16x8*)(Ab + (32 + (l & 15)) * 40 + (l >> 4) * 8);
        acc0 = __builtin_amdgcn_mfma_f32_16x16x32_bf16(a2, bfr, acc0, 0, 0, 0);
      }
    }
    if (ct + 1 < NTILE) STOREF();
    __syncthreads();
  }

  // epilogue: D[m=slot][c] -> af bf16 at (b*4+p)*704 + y*64 + c
  {
    const int c = 16 * nt + (l & 15);
    const int g = l >> 4;
    const float cb = conv_b[c];
    #pragma unroll
    for (int r = 0; r < 4; r++) {
      if (mhalf == 0) {
        int m0 = g * 4 + r;           // mt 0
        int p = m0 / FH, y = m0 - p * FH;
        float v = (sh_pos[m0] >= 0) ? (acc0[r] + cb) : 0.0f;
        af[(size_t)(b * NPROP + p) * FDIM + y * 64 + c] = f2bf(v);
        int m1 = 16 + g * 4 + r;      // mt 1
        p = m1 / FH; y = m1 - p * FH;
        v = (sh_pos[m1] >= 0) ? (acc1[r] + cb) : 0.0f;
        af[(size_t)(b * NPROP + p) * FDIM + y * 64 + c] = f2bf(v);
      } else {
        int m2 = 32 + g * 4 + r;      // mt 2
        if (m2 < 44) {
          int p = m2 / FH, y = m2 - p * FH;
          float v = (sh_pos[m2] >= 0) ? (acc0[r] + cb) : 0.0f;
          af[(size_t)(b * NPROP + p) * FDIM + y * 64 + c] = f2bf(v);
        }
      }
    }
  }
#undef LOADF
#undef STOREF
#undef LOADB
}

// ---------------- Kernel 2: head GEMM (MFMA) + attention + assembly ------
// grid = 128 blocks (4 batches each), 256 threads (4 waves).
// Y[16 x 160] = A[16 x 704] x Wc^T;  wave w owns n-tiles {w, w+4, w+8}.
__global__ __launch_bounds__(256) void k_head(
    const unsigned short* __restrict__ af, const float* __restrict__ xs,
    const unsigned short* __restrict__ Wc,
    const float* __restrict__ att_b, const float* __restrict__ cls_b,
    const float* __restrict__ reg_b, float* __restrict__ out)
{
  __shared__ __align__(16) unsigned short A_s[16 * 712];     // stride 712 bf16
  __shared__ __align__(16) unsigned short W_s[2][MROWS * 40]; // [n][k] stride 40
  __shared__ float Ys[16 * 161];
  __shared__ float Am[16][4];

  const int bg = blockIdx.x;
  const int t = threadIdx.x;
  const int l = t & 63;
  const int wid = t >> 6;

  // stage A (16 x 704 bf16) from ws, padded to stride 712
  {
    const unsigned* src = (const unsigned*)af + (size_t)bg * 16 * 352;
    for (int i = t; i < 16 * 352; i += 256) {
      int r = i / 352, ci = i - r * 352;
      ((unsigned*)A_s)[r * 356 + ci] = src[i];
    }
  }
  // stage W tile 0
  {
    #pragma unroll
    for (int e = t; e < 640; e += 256) {
      int n = e >> 2, jj = e & 3;
      uint4 ld = *(const uint4*)(Wc + n * FDIM + jj * 8);
      *(uint4*)(&W_s[0][n * 40 + jj * 8]) = ld;
    }
  }
  __syncthreads();

  f32x4 acc[3];
  acc[0] = (f32x4){0.f,0.f,0.f,0.f}; acc[1] = acc[0]; acc[2] = acc[0];

  for (int step = 0; step < 22; ++step) {
    int cur = step & 1;
    uint4 r0, r1, r2;
    bool h2 = (t + 512) < 640;
    if (step < 21) {
      int k0 = (step + 1) * 32;
      { int e = t;       int n = e >> 2, jj = e & 3; r0 = *(const uint4*)(Wc + n * FDIM + k0 + jj * 8); }
      { int e = t + 256; int n = e >> 2, jj = e & 3; r1 = *(const uint4*)(Wc + n * FDIM + k0 + jj * 8); }
      if (h2) { int e = t + 512; int n = e >> 2, jj = e & 3; r2 = *(const uint4*)(Wc + n * FDIM + k0 + jj * 8); }
    }
    bf16x8 a = *(const bf16x8*)(A_s + (l & 15) * 712 + step * 32 + (l >> 4) * 8);
    #pragma unroll
    for (int j = 0; j < 3; j++) {
      int ntl = wid + 4 * j;
      if (ntl < 10) {
        bf16x8 bb = *(const bf16x8*)(&W_s[cur][(ntl * 16 + (l & 15)) * 40 + (l >> 4) * 8]);
        acc[j] = __builtin_amdgcn_mfma_f32_16x16x32_bf16(a, bb, acc[j], 0, 0, 0);
      }
    }
    if (step < 21) {
      { int e = t;       int n = e >> 2, jj = e & 3; *(uint4*)(&W_s[cur ^ 1][n * 40 + jj * 8]) = r0; }
      { int e = t + 256; int n = e >> 2, jj = e & 3; *(uint4*)(&W_s[cur ^ 1][n * 40 + jj * 8]) = r1; }
      if (h2) { int e = t + 512; int n = e >> 2, jj = e & 3; *(uint4*)(&W_s[cur ^ 1][n * 40 + jj * 8]) = r2; }
    }
    __syncthreads();
  }

  // write Y to LDS
  #pragma unroll
  for (int j = 0; j < 3; j++) {
    int ntl = wid + 4 * j;
    if (ntl < 10) {
      #pragma unroll
      for (int r = 0; r < 4; r++)
        Ys[((l >> 4) * 4 + r) * 161 + ntl * 16 + (l & 15)] = acc[j][r];
    }
  }
  __syncthreads();

  // softmax over 3 non-self anchors per row
  if (t < 16) {
    float s0 = Ys[t * 161 + 150] + att_b[0];
    float s1 = Ys[t * 161 + 151] + att_b[1];
    float s2 = Ys[t * 161 + 152] + att_b[2];
    float mx = fmaxf(s0, fmaxf(s1, s2));
    float e0 = expf(s0 - mx), e1 = expf(s1 - mx), e2 = expf(s2 - mx);
    float inv = 1.0f / (e0 + e1 + e2);
    float aa[3] = {e0 * inv, e1 * inv, e2 * inv};
    int p = t & 3;
    #pragma unroll
    for (int q = 0; q < NPROP; q++)
      Am[t][q] = (q == p) ? 0.0f : aa[(q < p) ? q : q - 1];
  }
  __syncthreads();

  // assemble outputs
  for (int d = t; d < 16 * 75; d += 256) {
    int row = d / 75, o = d - row * 75;
    float v = Ys[row * 161 + 75 + o];
    int base = row & ~3;
    #pragma unroll
    for (int q = 0; q < NPROP; q++) v += Am[row][q] * Ys[(base + q) * 161 + o];
    v += (o < 2) ? cls_b[o] : reg_b[o - 2];
    int grow = bg * 16 + row;
    int col = (o < 2) ? o : o + 2;
    if (o >= 3) v += xs[grow * SFULL + (o - 3)];
    out[grow * 77 + col] = v;
  }
}

extern "C" void kernel_launch(void* const* d_in, const int* in_sizes, int n_in,
                              void* d_out, int out_size, void* d_ws, size_t ws_size,
                              hipStream_t stream) {
  const float* feat   = (const float*)d_in[0];
  const float* rpn    = (const float*)d_in[1];
  const float* conv_w = (const float*)d_in[2];
  const float* conv_b = (const float*)d_in[3];
  const float* att_w  = (const float*)d_in[4];
  const float* att_b  = (const float*)d_in[5];
  const float* cls_w  = (const float*)d_in[6];
  const float* cls_b  = (const float*)d_in[7];
  const float* reg_w  = (const float*)d_in[8];
  const float* reg_b  = (const float*)d_in[9];
  float* out = (float*)d_out;

  char* ws = (char*)d_ws;
  unsigned short* af = (unsigned short*)ws;                       // 512*4*704*2 = 2,883,584 B
  float* xs = (float*)(ws + 2883584);                             // 512*4*72*4 = 589,824 B
  unsigned short* Wc = (unsigned short*)(ws + 2883584 + 589824);  // 160*704*2 = 225,280 B

  w_prep<<<MROWS, 256, 0, stream>>>(cls_w, reg_w, att_w, Wc);
  k_gconv<<<512, 512, 0, stream>>>(feat, rpn, conv_w, conv_b, af, xs, out);
  k_head<<<128, 256, 0, stream>>>(af, xs, Wc, att_b, cls_b, reg_b, out);
}

// Round 3
// 87.980 us; speedup vs baseline: 2.4855x; 1.3013x over previous
//
#include <hip/hip_runtime.h>
#include <math.h>

#define NPROP 4
#define SFULL 72
#define FH 11
#define FW 20
#define CB 512
#define FDIM 704   // CF*FH
#define HW 220     // FH*FW
#define CHT 32
#define NTILE 16   // CB/CHT
#define MROWS 160  // padded head-output rows (153 used)
#define CHUNKS 1760   // 16B chunks per feat tile = CHT*HW*4/16
#define FSLACK 7184   // floats per lds_f buffer incl. 576B overshoot slack

typedef __attribute__((ext_vector_type(8))) short bf16x8;
typedef __attribute__((ext_vector_type(4))) float f32x4;

__device__ __forceinline__ unsigned short f2bf(float x) {
  unsigned u = __float_as_uint(x);
  u += 0x7FFFu + ((u >> 16) & 1u);
  return (unsigned short)(u >> 16);
}

__device__ __forceinline__ void gload16(const float* g, float* l) {
  __builtin_amdgcn_global_load_lds(
      (const __attribute__((address_space(1))) void*)(g),
      (__attribute__((address_space(3))) void*)(l), 16, 0, 0);
}

// ---------------- w_prep: permute head weights to f' = y*64+c ordering ----
__global__ void w_prep(const float* __restrict__ cls_w, const float* __restrict__ reg_w,
                       const float* __restrict__ att_w, unsigned short* __restrict__ Wc) {
  const int m = blockIdx.x;
  const int t = threadIdx.x;
  const float* rowp = nullptr;
  if (m < 150) {
    int o = (m < 75) ? m : m - 75;
    int half = (m < 75) ? 0 : FDIM;
    rowp = ((o < 2) ? (cls_w + o * 2 * FDIM) : (reg_w + (o - 2) * 2 * FDIM)) + half;
  } else if (m < 153) {
    rowp = att_w + (m - 150) * FDIM;
  }
  for (int f = t; f < FDIM; f += 256) {
    float v = rowp ? rowp[f] : 0.0f;
    int fp = (f % FH) * 64 + (f / FH);   // f = c*11+y -> f' = y*64+c
    Wc[m * FDIM + fp] = f2bf(v);
  }
}

// ---------------- Kernel 1: geometry + gathered 1x1 conv via MFMA ---------
// Counted-vmcnt pipeline: global_load_lds(16B) double-buffered feat tiles,
// raw s_barrier, s_waitcnt vmcnt(4) (never 0 in steady loop). B fragments
// (conv_w) live in registers for the whole kernel.
__global__ __launch_bounds__(512, 4) void k_gconv(
    const float* __restrict__ feat, const float* __restrict__ rpn,
    const float* __restrict__ conv_w, const float* __restrict__ conv_b,
    unsigned short* __restrict__ af, float* __restrict__ xs_full,
    float* __restrict__ out)
{
  __shared__ __align__(16) float lds_f[2][FSLACK];      // 2 x 28736 B
  __shared__ __align__(16) unsigned A_lds[2][48 * 20];  // bf16 [48][40]
  __shared__ float sh_sx[NPROP], sh_sy[NPROP], sh_it[NPROP];
  __shared__ int   sh_pos[48];

  const int b = blockIdx.x;
  const int t = threadIdx.x;
  const int l = t & 63;
  const int wid = t >> 6;
  const int nt = wid & 3;
  const int mhalf = wid >> 2;

  // --- geometry ---
  if (t < NPROP) {
    const float* rp = rpn + (b * NPROP + t) * 4;
    float sx = rp[0] * (1.0f / 640.0f);
    float sy = rp[1] * (1.0f / 360.0f);
    float tn = tanf(rp[3] * 0.017453292519943295f);
    sh_sx[t] = sx; sh_sy[t] = sy; sh_it[t] = 1.0f / tn;
    out[(b * NPROP + t) * 77 + 2] = 1.0f - sy;
    out[(b * NPROP + t) * 77 + 3] = sx;
  }
  __syncthreads();
  if (t < NPROP * SFULL) {
    int p = t / SFULL, i = t - p * SFULL;
    float ay = 1.0f - (float)i * (1.0f / 71.0f);
    xs_full[(b * NPROP + p) * SFULL + i] =
        (sh_sx[p] + (sh_sy[p] - ay) * sh_it[p]) * 640.0f;
  }
  if (t < 48) {
    int ps = -1;
    if (t < NPROP * FH) {
      int p = t / FH, y = t - p * FH;
      float acy = 1.0f - (float)(10 - y) * 0.1f;
      float xc = (sh_sx[p] + (sh_sy[p] - acy) * sh_it[p]) * 640.0f;
      int ui = (int)rintf(xc * (1.0f / 32.0f));
      int cut = min(max(ui, 0), FW - 1);
      ps = ((ui < 0) | (ui > FW)) ? -1 : (y * FW + cut);
    }
    sh_pos[t] = ps;
  }

  // --- B fragments (conv_w) into registers, bf16, all 16 K-tiles ---
  bf16x8 bfr[NTILE];
  {
    const float* wp = conv_w + (16 * nt + (l & 15)) * CB + (l >> 4) * 8;
    #pragma unroll
    for (int ct = 0; ct < NTILE; ct++) {
      float4 u = *(const float4*)(wp + ct * CHT);
      float4 v = *(const float4*)(wp + ct * CHT + 4);
      bfr[ct][0] = (short)f2bf(u.x); bfr[ct][1] = (short)f2bf(u.y);
      bfr[ct][2] = (short)f2bf(u.z); bfr[ct][3] = (short)f2bf(u.w);
      bfr[ct][4] = (short)f2bf(v.x); bfr[ct][5] = (short)f2bf(v.y);
      bfr[ct][6] = (short)f2bf(v.z); bfr[ct][7] = (short)f2bf(v.w);
    }
  }
  __syncthreads();   // sh_pos visible; drains all prologue VMEM (vmcnt=0)

  const float* fb = feat + (size_t)b * (CB * HW);

  // Each wave stages 220 chunks of 16B: 4 calls, last overlaps next wave
  // (duplicate identical writes, benign); overshoot clamped into slack.
#define STAGE(ct, buf) { \
    const float* gsrc = fb + (size_t)(ct) * (CHT * HW); \
    _Pragma("unroll") \
    for (int k = 0; k < 4; k++) { \
      int chunk = 220 * wid + 64 * k + l; \
      int cg = (chunk < CHUNKS) ? chunk : 0; \
      gload16(gsrc + cg * 4, &lds_f[buf][(220 * wid + 64 * k) * 4]); \
    } }

  STAGE(0, 0);   // only outstanding VMEM now: 4

  f32x4 acc0 = {0.f, 0.f, 0.f, 0.f}, acc1 = {0.f, 0.f, 0.f, 0.f};

  #pragma unroll
  for (int ct = 0; ct < NTILE; ct++) {
    const int cur = ct & 1;
    if (ct + 1 < NTILE) {
      STAGE(ct + 1, cur ^ 1);                       // 4 newer in flight
      asm volatile("s_waitcnt vmcnt(4)" ::: "memory");  // tile ct done (own)
    } else {
      asm volatile("s_waitcnt vmcnt(0)" ::: "memory");
    }
    __builtin_amdgcn_sched_barrier(0);
    __builtin_amdgcn_s_barrier();                   // tile ct staged (all waves)
    __builtin_amdgcn_sched_barrier(0);

    // gather 44 columns -> bf16 A tile (768 packed entries)
    #pragma unroll
    for (int e0 = 0; e0 < 2; e0++) {
      int e = t + 512 * e0;
      if (e < 768) {
        int s = e >> 4, kp = e & 15;
        int pos = sh_pos[s];
        int pp = pos < 0 ? 0 : pos;
        float lo = lds_f[cur][(2 * kp) * HW + pp];
        float hi = lds_f[cur][(2 * kp + 1) * HW + pp];
        unsigned pk = (pos < 0) ? 0u
          : ((unsigned)f2bf(lo) | ((unsigned)f2bf(hi) << 16));
        A_lds[cur][s * 20 + kp] = pk;
      }
    }
    asm volatile("s_waitcnt lgkmcnt(0)" ::: "memory");
    __builtin_amdgcn_sched_barrier(0);
    __builtin_amdgcn_s_barrier();                   // A ready
    __builtin_amdgcn_sched_barrier(0);

    const unsigned short* Ab = (const unsigned short*)A_lds[cur];
    if (mhalf == 0) {
      bf16x8 a0 = *(const bf16x8*)(Ab + (0 + (l & 15)) * 40 + (l >> 4) * 8);
      bf16x8 a1 = *(const bf16x8*)(Ab + (16 + (l & 15)) * 40 + (l >> 4) * 8);
      acc0 = __builtin_amdgcn_mfma_f32_16x16x32_bf16(a0, bfr[ct], acc0, 0, 0, 0);
      acc1 = __builtin_amdgcn_mfma_f32_16x16x32_bf16(a1, bfr[ct], acc1, 0, 0, 0);
    } else {
      bf16x8 a2 = *(const bf16x8*)(Ab + (32 + (l & 15)) * 40 + (l >> 4) * 8);
      acc0 = __builtin_amdgcn_mfma_f32_16x16x32_bf16(a2, bfr[ct], acc0, 0, 0, 0);
    }
  }
#undef STAGE

  // epilogue: D[m=slot][c] -> af bf16 at (b*4+p)*704 + y*64 + c
  {
    const int c = 16 * nt + (l & 15);
    const int g = l >> 4;
    const float cb = conv_b[c];
    #pragma unroll
    for (int r = 0; r < 4; r++) {
      if (mhalf == 0) {
        int m0 = g * 4 + r;
        int p = m0 / FH, y = m0 - p * FH;
        float v = (sh_pos[m0] >= 0) ? (acc0[r] + cb) : 0.0f;
        af[(size_t)(b * NPROP + p) * FDIM + y * 64 + c] = f2bf(v);
        int m1 = 16 + g * 4 + r;
        p = m1 / FH; y = m1 - p * FH;
        v = (sh_pos[m1] >= 0) ? (acc1[r] + cb) : 0.0f;
        af[(size_t)(b * NPROP + p) * FDIM + y * 64 + c] = f2bf(v);
      } else {
        int m2 = 32 + g * 4 + r;
        if (m2 < 44) {
          int p = m2 / FH, y = m2 - p * FH;
          float v = (sh_pos[m2] >= 0) ? (acc0[r] + cb) : 0.0f;
          af[(size_t)(b * NPROP + p) * FDIM + y * 64 + c] = f2bf(v);
        }
      }
    }
  }
}

// ---------------- Kernel 2: head GEMM (MFMA) + attention + assembly ------
__global__ __launch_bounds__(256) void k_head(
    const unsigned short* __restrict__ af, const float* __restrict__ xs,
    const unsigned short* __restrict__ Wc,
    const float* __restrict__ att_b, const float* __restrict__ cls_b,
    const float* __restrict__ reg_b, float* __restrict__ out)
{
  __shared__ __align__(16) unsigned short A_s[16 * 712];      // stride 712 bf16
  __shared__ __align__(16) unsigned short W_s[2][MROWS * 40]; // [n][k] stride 40
  __shared__ float Ys[16 * 161];
  __shared__ float Am[16][4];

  const int bg = blockIdx.x;
  const int t = threadIdx.x;
  const int l = t & 63;
  const int wid = t >> 6;

  {
    const unsigned* src = (const unsigned*)af + (size_t)bg * 16 * 352;
    for (int i = t; i < 16 * 352; i += 256) {
      int r = i / 352, ci = i - r * 352;
      ((unsigned*)A_s)[r * 356 + ci] = src[i];
    }
  }
  {
    #pragma unroll
    for (int e = t; e < 640; e += 256) {
      int n = e >> 2, jj = e & 3;
      uint4 ld = *(const uint4*)(Wc + n * FDIM + jj * 8);
      *(uint4*)(&W_s[0][n * 40 + jj * 8]) = ld;
    }
  }
  __syncthreads();

  f32x4 acc[3];
  acc[0] = (f32x4){0.f,0.f,0.f,0.f}; acc[1] = acc[0]; acc[2] = acc[0];

  for (int step = 0; step < 22; ++step) {
    int cur = step & 1;
    uint4 r0, r1, r2;
    bool h2 = (t + 512) < 640;
    if (step < 21) {
      int k0 = (step + 1) * 32;
      { int e = t;       int n = e >> 2, jj = e & 3; r0 = *(const uint4*)(Wc + n * FDIM + k0 + jj * 8); }
      { int e = t + 256; int n = e >> 2, jj = e & 3; r1 = *(const uint4*)(Wc + n * FDIM + k0 + jj * 8); }
      if (h2) { int e = t + 512; int n = e >> 2, jj = e & 3; r2 = *(const uint4*)(Wc + n * FDIM + k0 + jj * 8); }
    }
    bf16x8 a = *(const bf16x8*)(A_s + (l & 15) * 712 + step * 32 + (l >> 4) * 8);
    #pragma unroll
    for (int j = 0; j < 3; j++) {
      int ntl = wid + 4 * j;
      if (ntl < 10) {
        bf16x8 bb = *(const bf16x8*)(&W_s[cur][(ntl * 16 + (l & 15)) * 40 + (l >> 4) * 8]);
        acc[j] = __builtin_amdgcn_mfma_f32_16x16x32_bf16(a, bb, acc[j], 0, 0, 0);
      }
    }
    if (step < 21) {
      { int e = t;       int n = e >> 2, jj = e & 3; *(uint4*)(&W_s[cur ^ 1][n * 40 + jj * 8]) = r0; }
      { int e = t + 256; int n = e >> 2, jj = e & 3; *(uint4*)(&W_s[cur ^ 1][n * 40 + jj * 8]) = r1; }
      if (h2) { int e = t + 512; int n = e >> 2, jj = e & 3; *(uint4*)(&W_s[cur ^ 1][n * 40 + jj * 8]) = r2; }
    }
    __syncthreads();
  }

  #pragma unroll
  for (int j = 0; j < 3; j++) {
    int ntl = wid + 4 * j;
    if (ntl < 10) {
      #pragma unroll
      for (int r = 0; r < 4; r++)
        Ys[((l >> 4) * 4 + r) * 161 + ntl * 16 + (l & 15)] = acc[j][r];
    }
  }
  __syncthreads();

  if (t < 16) {
    float s0 = Ys[t * 161 + 150] + att_b[0];
    float s1 = Ys[t * 161 + 151] + att_b[1];
    float s2 = Ys[t * 161 + 152] + att_b[2];
    float mx = fmaxf(s0, fmaxf(s1, s2));
    float e0 = expf(s0 - mx), e1 = expf(s1 - mx), e2 = expf(s2 - mx);
    float inv = 1.0f / (e0 + e1 + e2);
    float aa[3] = {e0 * inv, e1 * inv, e2 * inv};
    int p = t & 3;
    #pragma unroll
    for (int q = 0; q < NPROP; q++)
      Am[t][q] = (q == p) ? 0.0f : aa[(q < p) ? q : q - 1];
  }
  __syncthreads();

  for (int d = t; d < 16 * 75; d += 256) {
    int row = d / 75, o = d - row * 75;
    float v = Ys[row * 161 + 75 + o];
    int base = row & ~3;
    #pragma unroll
    for (int q = 0; q < NPROP; q++) v += Am[row][q] * Ys[(base + q) * 161 + o];
    v += (o < 2) ? cls_b[o] : reg_b[o - 2];
    int grow = bg * 16 + row;
    int col = (o < 2) ? o : o + 2;
    if (o >= 3) v += xs[grow * SFULL + (o - 3)];
    out[grow * 77 + col] = v;
  }
}

extern "C" void kernel_launch(void* const* d_in, const int* in_sizes, int n_in,
                              void* d_out, int out_size, void* d_ws, size_t ws_size,
                              hipStream_t stream) {
  const float* feat   = (const float*)d_in[0];
  const float* rpn    = (const float*)d_in[1];
  const float* conv_w = (const float*)d_in[2];
  const float* conv_b = (const float*)d_in[3];
  const float* att_w  = (const float*)d_in[4];
  const float* att_b  = (const float*)d_in[5];
  const float* cls_w  = (const float*)d_in[6];
  const float* cls_b  = (const float*)d_in[7];
  const float* reg_w  = (const float*)d_in[8];
  const float* reg_b  = (const float*)d_in[9];
  float* out = (float*)d_out;

  char* ws = (char*)d_ws;
  unsigned short* af = (unsigned short*)ws;                       // 2,883,584 B
  float* xs = (float*)(ws + 2883584);                             // 589,824 B
  unsigned short* Wc = (unsigned short*)(ws + 2883584 + 589824);  // 225,280 B

  w_prep<<<MROWS, 256, 0, stream>>>(cls_w, reg_w, att_w, Wc);
  k_gconv<<<512, 512, 0, stream>>>(feat, rpn, conv_w, conv_b, af, xs, out);
  k_head<<<128, 256, 0, stream>>>(af, xs, Wc, att_b, cls_b, reg_b, out);
}

// Round 4
// 71.384 us; speedup vs baseline: 3.0634x; 1.2325x over previous
//
#include <hip/hip_runtime.h>
#include <math.h>

#define NPROP 4
#define SFULL 72
#define FH 11
#define FW 20
#define CB 512
#define FDIM 704   // CF*FH
#define HW 220     // FH*FW
#define CHT 32
#define NTILE 16   // CB/CHT
#define MROWS 160  // padded head-output rows (153 used)

typedef __attribute__((ext_vector_type(8))) short bf16x8;
typedef __attribute__((ext_vector_type(4))) float f32x4;

__device__ __forceinline__ unsigned short f2bf(float x) {
  unsigned u = __float_as_uint(x);
  u += 0x7FFFu + ((u >> 16) & 1u);
  return (unsigned short)(u >> 16);
}

__device__ __forceinline__ void gload16(const void* g, void* l) {
  __builtin_amdgcn_global_load_lds(
      (const __attribute__((address_space(1))) void*)(g),
      (__attribute__((address_space(3))) void*)(l), 16, 0, 0);
}

// ---------------- w_prep: permute head weights to f' = y*64+c ordering ----
__global__ void w_prep(const float* __restrict__ cls_w, const float* __restrict__ reg_w,
                       const float* __restrict__ att_w, unsigned short* __restrict__ Wc) {
  const int m = blockIdx.x;
  const int t = threadIdx.x;
  const float* rowp = nullptr;
  if (m < 150) {
    int o = (m < 75) ? m : m - 75;
    int half = (m < 75) ? 0 : FDIM;
    rowp = ((o < 2) ? (cls_w + o * 2 * FDIM) : (reg_w + (o - 2) * 2 * FDIM)) + half;
  } else if (m < 153) {
    rowp = att_w + (m - 150) * FDIM;
  }
  for (int f = t; f < FDIM; f += 256) {
    float v = rowp ? rowp[f] : 0.0f;
    int fp = (f % FH) * 64 + (f / FH);   // f = c*11+y -> f' = y*64+c
    Wc[m * FDIM + fp] = f2bf(v);
  }
}

// ---------------- k_wprep2: conv_w -> bf16 B-frag layout [kg][c][8] -------
// Wb2[kg*512 + c*8 + i] = bf16(conv_w[c][kg*8+i]), kg in [0,64)
__global__ void k_wprep2(const float* __restrict__ conv_w, unsigned short* __restrict__ Wb2) {
  const int kg = blockIdx.x;
  const int t = threadIdx.x;
  const int c = t >> 3, i = t & 7;
  Wb2[kg * 512 + t] = f2bf(conv_w[c * CB + kg * 8 + i]);
}

// ---------------- Kernel 1: geometry + gathered 1x1 conv via MFMA ---------
// Register-streamed feat (depth-3, vmcnt(8) steady), direct scatter of the
// 44 needed columns into a tiny bf16 A-buffer; ONE barrier per K-tile.
// conv_w fragments live in a 64KB LDS buffer (ds_read_b128 per tile).
__global__ __launch_bounds__(512, 4) void k_gconv(
    const float* __restrict__ feat, const float* __restrict__ rpn,
    const unsigned short* __restrict__ Wb2, const float* __restrict__ conv_b,
    unsigned short* __restrict__ af, float* __restrict__ xs_full,
    float* __restrict__ out)
{
  __shared__ __align__(16) unsigned short W2[64 * 512];   // 64KB B-frags
  __shared__ __align__(16) unsigned short As[2 * 48 * 40]; // 7.5KB A dbuf
  __shared__ float sh_sx[NPROP], sh_sy[NPROP], sh_it[NPROP];
  __shared__ int   sh_pos[48];
  __shared__ int   hcnt[55];
  __shared__ unsigned hword[55];

  const int b = blockIdx.x;
  const int t = threadIdx.x;
  const int l = t & 63;
  const int wid = t >> 6;
  const int nt = wid & 3;
  const int mhalf = wid >> 2;
  const int q = l >> 4, r = l & 15;

  // --- geometry ---
  if (t < NPROP) {
    const float* rp = rpn + (b * NPROP + t) * 4;
    float sx = rp[0] * (1.0f / 640.0f);
    float sy = rp[1] * (1.0f / 360.0f);
    float tn = tanf(rp[3] * 0.017453292519943295f);
    sh_sx[t] = sx; sh_sy[t] = sy; sh_it[t] = 1.0f / tn;
    out[(b * NPROP + t) * 77 + 2] = 1.0f - sy;
    out[(b * NPROP + t) * 77 + 3] = sx;
  }
  __syncthreads();
  if (t < NPROP * SFULL) {
    int p = t / SFULL, i = t - p * SFULL;
    float ay = 1.0f - (float)i * (1.0f / 71.0f);
    xs_full[(b * NPROP + p) * SFULL + i] =
        (sh_sx[p] + (sh_sy[p] - ay) * sh_it[p]) * 640.0f;
  }
  if (t < 48) {
    int ps = -1;
    if (t < NPROP * FH) {
      int p = t / FH, y = t - p * FH;
      float acy = 1.0f - (float)(10 - y) * 0.1f;
      float xc = (sh_sx[p] + (sh_sy[p] - acy) * sh_it[p]) * 640.0f;
      int ui = (int)rintf(xc * (1.0f / 32.0f));
      int cut = min(max(ui, 0), FW - 1);
      ps = ((ui < 0) | (ui > FW)) ? -1 : (y * FW + cut);
    }
    sh_pos[t] = ps;
  }
  __syncthreads();

  // --- hit lists: for each 4-float window j in [0,55): slots hitting it ---
  // max 4 hits per window (one per proposal at the window's y)
  if (t < 55) {
    int cnt = 0; unsigned w = 0;
    for (int s = 0; s < 44; s++) {
      int p = sh_pos[s];
      if (p >= 0 && (p >> 2) == t) {
        w |= ((unsigned)(s | ((p & 3) << 6))) << (8 * cnt);
        cnt++;
      }
    }
    hcnt[t] = cnt; hword[t] = w;
  }
  __syncthreads();

  // --- per-thread chunk descriptors (fixed across all 16 tiles) ---
  int hn[4]; unsigned hwd[4]; int chS[4]; int cidg[4];
  #pragma unroll
  for (int k = 0; k < 4; k++) {
    int c = t + 512 * k;
    bool ok = (c < 1760);
    cidg[k] = ok ? c : 0;
    int j = c % 55;
    chS[k] = c / 55;
    hn[k]  = ok ? hcnt[j] : 0;
    hwd[k] = hword[j];
  }

  const float* fb = feat + (size_t)b * (CB * HW);

  // --- issue W2 staging (8 gload16, oldest in queue) ---
  #pragma unroll
  for (int k = 0; k < 8; k++) {
    int chunk = t + 512 * k;
    gload16(Wb2 + chunk * 8, (void*)&W2[chunk * 8]);
  }
  __builtin_amdgcn_sched_barrier(0);

  // --- issue feat tiles 0,1,2 into registers (depth-3) ---
  float4 pf[3][4];
  #pragma unroll
  for (int s = 0; s < 3; s++) {
    const float4* g = (const float4*)(fb + s * (CHT * HW));
    #pragma unroll
    for (int k = 0; k < 4; k++) pf[s][k] = g[cidg[k]];
    __builtin_amdgcn_sched_barrier(0);
  }

  f32x4 acc0 = {0.f, 0.f, 0.f, 0.f}, acc1 = {0.f, 0.f, 0.f, 0.f};
  const int cW = 16 * nt + r;

  #pragma unroll
  for (int ct = 0; ct < NTILE; ct++) {
    // wait: tile ct's 4 loads (and, at ct=0, all W2 gload16s) complete
    if (ct <= 13)      asm volatile("s_waitcnt vmcnt(8)" ::: "memory");
    else if (ct == 14) asm volatile("s_waitcnt vmcnt(4)" ::: "memory");
    else               asm volatile("s_waitcnt vmcnt(0)" ::: "memory");
    __builtin_amdgcn_sched_barrier(0);

    // scatter hits of tile ct -> As[ct&1] (bf16)
    unsigned short* Asb = As + (ct & 1) * 1920;
    #pragma unroll
    for (int k = 0; k < 4; k++) {
      float4 v4 = pf[ct % 3][k];
      int n = hn[k]; unsigned wd = hwd[k]; int ch = chS[k];
      #pragma unroll
      for (int h = 0; h < 4; h++) {
        if (h < n) {
          unsigned byte = (wd >> (8 * h)) & 255u;
          int s = (int)(byte & 63u), off = (int)(byte >> 6);
          float v = (off == 0) ? v4.x : (off == 1) ? v4.y : (off == 2) ? v4.z : v4.w;
          Asb[s * 40 + ch] = f2bf(v);
        }
      }
    }
    // prefetch tile ct+3 into the register set just consumed
    if (ct + 3 < NTILE) {
      const float4* g = (const float4*)(fb + (ct + 3) * (CHT * HW));
      #pragma unroll
      for (int k = 0; k < 4; k++) pf[ct % 3][k] = g[cidg[k]];
    }
    asm volatile("s_waitcnt lgkmcnt(0)" ::: "memory");
    __builtin_amdgcn_sched_barrier(0);
    __builtin_amdgcn_s_barrier();          // A tile visible to all waves
    __builtin_amdgcn_sched_barrier(0);

    // fragments + MFMA
    bf16x8 bw = *(const bf16x8*)&W2[((ct * 4 + q) * 64 + cW) * 8];
    if (mhalf == 0) {
      bf16x8 a0 = *(const bf16x8*)&Asb[(0 + r) * 40 + q * 8];
      bf16x8 a1 = *(const bf16x8*)&Asb[(16 + r) * 40 + q * 8];
      asm volatile("s_waitcnt lgkmcnt(0)" ::: "memory");
      __builtin_amdgcn_sched_barrier(0);
      acc0 = __builtin_amdgcn_mfma_f32_16x16x32_bf16(a0, bw, acc0, 0, 0, 0);
      acc1 = __builtin_amdgcn_mfma_f32_16x16x32_bf16(a1, bw, acc1, 0, 0, 0);
    } else {
      bf16x8 a2 = *(const bf16x8*)&Asb[(32 + r) * 40 + q * 8];
      asm volatile("s_waitcnt lgkmcnt(0)" ::: "memory");
      __builtin_amdgcn_sched_barrier(0);
      acc0 = __builtin_amdgcn_mfma_f32_16x16x32_bf16(a2, bw, acc0, 0, 0, 0);
    }
  }

  // epilogue: D[m=slot][c] -> af bf16 at (b*4+p)*704 + y*64 + c
  {
    const int c = cW;
    const int g = q;
    const float cb = conv_b[c];
    #pragma unroll
    for (int rr = 0; rr < 4; rr++) {
      if (mhalf == 0) {
        int m0 = g * 4 + rr;
        int p = m0 / FH, y = m0 - p * FH;
        float v = (sh_pos[m0] >= 0) ? (acc0[rr] + cb) : 0.0f;
        af[(size_t)(b * NPROP + p) * FDIM + y * 64 + c] = f2bf(v);
        int m1 = 16 + g * 4 + rr;
        p = m1 / FH; y = m1 - p * FH;
        v = (sh_pos[m1] >= 0) ? (acc1[rr] + cb) : 0.0f;
        af[(size_t)(b * NPROP + p) * FDIM + y * 64 + c] = f2bf(v);
      } else {
        int m2 = 32 + g * 4 + rr;
        if (m2 < 44) {
          int p = m2 / FH, y = m2 - p * FH;
          float v = (sh_pos[m2] >= 0) ? (acc0[rr] + cb) : 0.0f;
          af[(size_t)(b * NPROP + p) * FDIM + y * 64 + c] = f2bf(v);
        }
      }
    }
  }
}

// ---------------- Kernel 2: head GEMM (MFMA) + attention + assembly ------
__global__ __launch_bounds__(256) void k_head(
    const unsigned short* __restrict__ af, const float* __restrict__ xs,
    const unsigned short* __restrict__ Wc,
    const float* __restrict__ att_b, const float* __restrict__ cls_b,
    const float* __restrict__ reg_b, float* __restrict__ out)
{
  __shared__ __align__(16) unsigned short A_s[16 * 712];      // stride 712 bf16
  __shared__ __align__(16) unsigned short W_s[2][MROWS * 40]; // [n][k] stride 40
  __shared__ float Ys[16 * 161];
  __shared__ float Am[16][4];

  const int bg = blockIdx.x;
  const int t = threadIdx.x;
  const int l = t & 63;
  const int wid = t >> 6;

  {
    const unsigned* src = (const unsigned*)af + (size_t)bg * 16 * 352;
    for (int i = t; i < 16 * 352; i += 256) {
      int r = i / 352, ci = i - r * 352;
      ((unsigned*)A_s)[r * 356 + ci] = src[i];
    }
  }
  {
    #pragma unroll
    for (int e = t; e < 640; e += 256) {
      int n = e >> 2, jj = e & 3;
      uint4 ld = *(const uint4*)(Wc + n * FDIM + jj * 8);
      *(uint4*)(&W_s[0][n * 40 + jj * 8]) = ld;
    }
  }
  __syncthreads();

  f32x4 acc[3];
  acc[0] = (f32x4){0.f,0.f,0.f,0.f}; acc[1] = acc[0]; acc[2] = acc[0];

  for (int step = 0; step < 22; ++step) {
    int cur = step & 1;
    uint4 r0, r1, r2;
    bool h2 = (t + 512) < 640;
    if (step < 21) {
      int k0 = (step + 1) * 32;
      { int e = t;       int n = e >> 2, jj = e & 3; r0 = *(const uint4*)(Wc + n * FDIM + k0 + jj * 8); }
      { int e = t + 256; int n = e >> 2, jj = e & 3; r1 = *(const uint4*)(Wc + n * FDIM + k0 + jj * 8); }
      if (h2) { int e = t + 512; int n = e >> 2, jj = e & 3; r2 = *(const uint4*)(Wc + n * FDIM + k0 + jj * 8); }
    }
    bf16x8 a = *(const bf16x8*)(A_s + (l & 15) * 712 + step * 32 + (l >> 4) * 8);
    #pragma unroll
    for (int j = 0; j < 3; j++) {
      int ntl = wid + 4 * j;
      if (ntl < 10) {
        bf16x8 bb = *(const bf16x8*)(&W_s[cur][(ntl * 16 + (l & 15)) * 40 + (l >> 4) * 8]);
        acc[j] = __builtin_amdgcn_mfma_f32_16x16x32_bf16(a, bb, acc[j], 0, 0, 0);
      }
    }
    if (step < 21) {
      { int e = t;       int n = e >> 2, jj = e & 3; *(uint4*)(&W_s[cur ^ 1][n * 40 + jj * 8]) = r0; }
      { int e = t + 256; int n = e >> 2, jj = e & 3; *(uint4*)(&W_s[cur ^ 1][n * 40 + jj * 8]) = r1; }
      if (h2) { int e = t + 512; int n = e >> 2, jj = e & 3; *(uint4*)(&W_s[cur ^ 1][n * 40 + jj * 8]) = r2; }
    }
    __syncthreads();
  }

  #pragma unroll
  for (int j = 0; j < 3; j++) {
    int ntl = wid + 4 * j;
    if (ntl < 10) {
      #pragma unroll
      for (int r = 0; r < 4; r++)
        Ys[((l >> 4) * 4 + r) * 161 + ntl * 16 + (l & 15)] = acc[j][r];
    }
  }
  __syncthreads();

  if (t < 16) {
    float s0 = Ys[t * 161 + 150] + att_b[0];
    float s1 = Ys[t * 161 + 151] + att_b[1];
    float s2 = Ys[t * 161 + 152] + att_b[2];
    float mx = fmaxf(s0, fmaxf(s1, s2));
    float e0 = expf(s0 - mx), e1 = expf(s1 - mx), e2 = expf(s2 - mx);
    float inv = 1.0f / (e0 + e1 + e2);
    float aa[3] = {e0 * inv, e1 * inv, e2 * inv};
    int p = t & 3;
    #pragma unroll
    for (int qq = 0; qq < NPROP; qq++)
      Am[t][qq] = (qq == p) ? 0.0f : aa[(qq < p) ? qq : qq - 1];
  }
  __syncthreads();

  for (int d = t; d < 16 * 75; d += 256) {
    int row = d / 75, o = d - row * 75;
    float v = Ys[row * 161 + 75 + o];
    int base = row & ~3;
    #pragma unroll
    for (int qq = 0; qq < NPROP; qq++) v += Am[row][qq] * Ys[(base + qq) * 161 + o];
    v += (o < 2) ? cls_b[o] : reg_b[o - 2];
    int grow = bg * 16 + row;
    int col = (o < 2) ? o : o + 2;
    if (o >= 3) v += xs[grow * SFULL + (o - 3)];
    out[grow * 77 + col] = v;
  }
}

extern "C" void kernel_launch(void* const* d_in, const int* in_sizes, int n_in,
                              void* d_out, int out_size, void* d_ws, size_t ws_size,
                              hipStream_t stream) {
  const float* feat   = (const float*)d_in[0];
  const float* rpn    = (const float*)d_in[1];
  const float* conv_w = (const float*)d_in[2];
  const float* conv_b = (const float*)d_in[3];
  const float* att_w  = (const float*)d_in[4];
  const float* att_b  = (const float*)d_in[5];
  const float* cls_w  = (const float*)d_in[6];
  const float* cls_b  = (const float*)d_in[7];
  const float* reg_w  = (const float*)d_in[8];
  const float* reg_b  = (const float*)d_in[9];
  float* out = (float*)d_out;

  char* ws = (char*)d_ws;
  unsigned short* af  = (unsigned short*)ws;                        // 2,883,584 B
  float* xs           = (float*)(ws + 2883584);                     // 589,824 B
  unsigned short* Wc  = (unsigned short*)(ws + 2883584 + 589824);   // 225,280 B
  unsigned short* Wb2 = (unsigned short*)(ws + 2883584 + 589824 + 225280); // 65,536 B

  w_prep<<<MROWS, 256, 0, stream>>>(cls_w, reg_w, att_w, Wc);
  k_wprep2<<<64, 512, 0, stream>>>(conv_w, Wb2);
  k_gconv<<<512, 512, 0, stream>>>(feat, rpn, Wb2, conv_b, af, xs, out);
  k_head<<<128, 256, 0, stream>>>(af, xs, Wc, att_b, cls_b, reg_b, out);
}

// Round 5
// 67.253 us; speedup vs baseline: 3.2516x; 1.0614x over previous
//
#include <hip/hip_runtime.h>
#include <math.h>

#define NPROP 4
#define SFULL 72
#define FH 11
#define FW 20
#define CB 512
#define FDIM 704   // CF*FH
#define HW 220     // FH*FW
#define CHT 32
#define NTILE 16   // CB/CHT
#define MROWS 160  // padded head-output rows (153 used)

typedef __attribute__((ext_vector_type(8))) short bf16x8;
typedef __attribute__((ext_vector_type(4))) float f32x4;

__device__ __forceinline__ unsigned short f2bf(float x) {
  unsigned u = __float_as_uint(x);
  u += 0x7FFFu + ((u >> 16) & 1u);
  return (unsigned short)(u >> 16);
}
// rounded bf16 in the TOP 16 bits
__device__ __forceinline__ unsigned bfbits(float x) {
  unsigned u = __float_as_uint(x);
  return u + 0x7FFFu + ((u >> 16) & 1u);
}

__device__ __forceinline__ void gload16(const void* g, void* l) {
  __builtin_amdgcn_global_load_lds(
      (const __attribute__((address_space(1))) void*)(g),
      (__attribute__((address_space(3))) void*)(l), 16, 0, 0);
}

// ---------------- k_prep: head-weight permute + conv_w B-frag layout ------
// blocks [0,160): Wc[m][f'] bf16 (f = c*11+y -> f' = y*64+c)
// blocks [160,224): Wb2[kg*512 + c*8 + i] = bf16(conv_w[c][kg*8+i])
__global__ void k_prep(const float* __restrict__ cls_w, const float* __restrict__ reg_w,
                       const float* __restrict__ att_w, const float* __restrict__ conv_w,
                       unsigned short* __restrict__ Wc, unsigned short* __restrict__ Wb2) {
  const int blk = blockIdx.x;
  const int t = threadIdx.x;
  if (blk < MROWS) {
    const int m = blk;
    const float* rowp = nullptr;
    if (m < 150) {
      int o = (m < 75) ? m : m - 75;
      int half = (m < 75) ? 0 : FDIM;
      rowp = ((o < 2) ? (cls_w + o * 2 * FDIM) : (reg_w + (o - 2) * 2 * FDIM)) + half;
    } else if (m < 153) {
      rowp = att_w + (m - 150) * FDIM;
    }
    for (int f = t; f < FDIM; f += 256) {
      float v = rowp ? rowp[f] : 0.0f;
      int fp = (f % FH) * 64 + (f / FH);
      Wc[m * FDIM + fp] = f2bf(v);
    }
  } else {
    const int kg = blk - MROWS;
    #pragma unroll
    for (int e0 = 0; e0 < 2; e0++) {
      int e = t + 256 * e0;
      Wb2[kg * 512 + e] = f2bf(conv_w[(e >> 3) * CB + kg * 8 + (e & 7)]);
    }
  }
}

// ---------------- Kernel 1: geometry + gathered 1x1 conv via MFMA ---------
// Register-streamed feat (depth-3, vmcnt(8) steady), pack-once scatter of
// the 44 needed columns into a tiny bf16 A-buffer; ONE barrier per K-tile.
__global__ __launch_bounds__(512, 4) void k_gconv(
    const float* __restrict__ feat, const float* __restrict__ rpn,
    const unsigned short* __restrict__ Wb2, const float* __restrict__ conv_b,
    unsigned short* __restrict__ af, float* __restrict__ xs_full,
    float* __restrict__ out)
{
  __shared__ __align__(16) unsigned short W2[64 * 512];    // 64KB B-frags
  __shared__ __align__(16) unsigned short As[2 * 48 * 40]; // 7.5KB A dbuf
  __shared__ float sh_sx[NPROP], sh_sy[NPROP], sh_it[NPROP];
  __shared__ int   sh_pos[48];
  __shared__ int   hcnt[55];
  __shared__ unsigned hword[55];

  const int b = blockIdx.x;
  const int t = threadIdx.x;
  const int l = t & 63;
  const int wid = t >> 6;
  const int nt = wid & 3;
  const int mhalf = wid >> 2;
  const int q = l >> 4, r = l & 15;

  // --- geometry ---
  if (t < NPROP) {
    const float* rp = rpn + (b * NPROP + t) * 4;
    float sx = rp[0] * (1.0f / 640.0f);
    float sy = rp[1] * (1.0f / 360.0f);
    float tn = tanf(rp[3] * 0.017453292519943295f);
    sh_sx[t] = sx; sh_sy[t] = sy; sh_it[t] = 1.0f / tn;
    out[(b * NPROP + t) * 77 + 2] = 1.0f - sy;
    out[(b * NPROP + t) * 77 + 3] = sx;
  }
  __syncthreads();
  if (t < NPROP * SFULL) {
    int p = t / SFULL, i = t - p * SFULL;
    float ay = 1.0f - (float)i * (1.0f / 71.0f);
    xs_full[(b * NPROP + p) * SFULL + i] =
        (sh_sx[p] + (sh_sy[p] - ay) * sh_it[p]) * 640.0f;
  }
  if (t < 48) {
    int ps = -1;
    if (t < NPROP * FH) {
      int p = t / FH, y = t - p * FH;
      float acy = 1.0f - (float)(10 - y) * 0.1f;
      float xc = (sh_sx[p] + (sh_sy[p] - acy) * sh_it[p]) * 640.0f;
      int ui = (int)rintf(xc * (1.0f / 32.0f));
      int cut = min(max(ui, 0), FW - 1);
      ps = ((ui < 0) | (ui > FW)) ? -1 : (t % FH) * FW + cut;
    }
    sh_pos[t] = ps;
  }
  __syncthreads();

  // --- hit lists per 4-float window j in [0,55): byte = s | (p&3)<<6 ---
  if (t < 55) {
    int cnt = 0; unsigned w = 0;
    for (int s = 0; s < 44; s++) {
      int p = sh_pos[s];
      if (p >= 0 && (p >> 2) == t) {
        w |= ((unsigned)(s | ((p & 3) << 6))) << (8 * cnt);
        cnt++;
      }
    }
    hcnt[t] = cnt; hword[t] = w;
  }
  __syncthreads();

  // --- per-thread chunk descriptors (tile-invariant) ---
  // wave owns chunks [220*wid, 220*wid+220): lanes l, l+64, l+128, (l<28: l+192)
  int hn[4]; unsigned hwd[4]; int chS[4]; int cid[4];
  const int cbase = 220 * wid;
  #pragma unroll
  for (int k = 0; k < 4; k++) {
    int c = cbase + 64 * k + l;
    bool ok = (k < 3) || (l < 28);
    cid[k] = c;
    int j = c % 55;
    chS[k] = c / 55;
    hn[k]  = ok ? hcnt[j] : 0;
    hwd[k] = hword[j];
  }

  const float* fb = feat + (size_t)b * (CB * HW);

  // --- W2 staging: 8 gload16/thread (oldest in vm queue) ---
  #pragma unroll
  for (int k = 0; k < 8; k++) {
    int chunk = t + 512 * k;
    gload16(Wb2 + chunk * 8, (void*)&W2[chunk * 8]);
  }
  __builtin_amdgcn_sched_barrier(0);

  // --- feat tiles 0,1,2 into registers (depth-3, 4 VMEM instrs each) ---
  float4 pf[3][4];
  #pragma unroll
  for (int s = 0; s < 3; s++) {
    const float4* g = (const float4*)(fb + s * (CHT * HW));
    #pragma unroll
    for (int k = 0; k < 3; k++) pf[s][k] = g[cid[k]];
    if (l < 28) pf[s][3] = g[cid[3]];
    __builtin_amdgcn_sched_barrier(0);
  }

  f32x4 acc0 = {0.f, 0.f, 0.f, 0.f}, acc1 = {0.f, 0.f, 0.f, 0.f};
  const int cW = 16 * nt + r;

  #pragma unroll
  for (int ct = 0; ct < NTILE; ct++) {
    if (ct <= 13)      asm volatile("s_waitcnt vmcnt(8)" ::: "memory");
    else if (ct == 14) asm volatile("s_waitcnt vmcnt(4)" ::: "memory");
    else               asm volatile("s_waitcnt vmcnt(0)" ::: "memory");
    __builtin_amdgcn_sched_barrier(0);

    // scatter hits of tile ct -> As[ct&1]: pack chunk to bf16 once, extract
    unsigned short* Asb = As + (ct & 1) * 1920;
    #pragma unroll
    for (int k = 0; k < 4; k++) {
      int n = hn[k];
      if (n) {
        float4 v4 = pf[ct % 3][k];
        unsigned d0 = (bfbits(v4.x) >> 16) | (bfbits(v4.y) & 0xFFFF0000u);
        unsigned d1 = (bfbits(v4.z) >> 16) | (bfbits(v4.w) & 0xFFFF0000u);
        unsigned wd = hwd[k];
        #pragma unroll
        for (int h = 0; h < 4; h++) {
          if (h < n) {
            unsigned byte = (wd >> (8 * h)) & 255u;
            unsigned s = byte & 63u;
            unsigned sel = (byte & 128u) ? d1 : d0;
            unsigned short val = (byte & 64u) ? (unsigned short)(sel >> 16)
                                              : (unsigned short)sel;
            Asb[s * 40 + chS[k]] = val;
          }
        }
      }
    }
    // prefetch tile ct+3 into the register set just consumed
    if (ct + 3 < NTILE) {
      const float4* g = (const float4*)(fb + (ct + 3) * (CHT * HW));
      #pragma unroll
      for (int k = 0; k < 3; k++) pf[ct % 3][k] = g[cid[k]];
      if (l < 28) pf[ct % 3][3] = g[cid[3]];
    }
    asm volatile("s_waitcnt lgkmcnt(0)" ::: "memory");
    __builtin_amdgcn_sched_barrier(0);
    __builtin_amdgcn_s_barrier();          // A tile visible to all waves
    __builtin_amdgcn_sched_barrier(0);

    // fragments + MFMA
    bf16x8 bw = *(const bf16x8*)&W2[((ct * 4 + q) * 64 + cW) * 8];
    if (mhalf == 0) {
      bf16x8 a0 = *(const bf16x8*)&Asb[(0 + r) * 40 + q * 8];
      bf16x8 a1 = *(const bf16x8*)&Asb[(16 + r) * 40 + q * 8];
      asm volatile("s_waitcnt lgkmcnt(0)" ::: "memory");
      __builtin_amdgcn_sched_barrier(0);
      acc0 = __builtin_amdgcn_mfma_f32_16x16x32_bf16(a0, bw, acc0, 0, 0, 0);
      acc1 = __builtin_amdgcn_mfma_f32_16x16x32_bf16(a1, bw, acc1, 0, 0, 0);
    } else {
      bf16x8 a2 = *(const bf16x8*)&Asb[(32 + r) * 40 + q * 8];
      asm volatile("s_waitcnt lgkmcnt(0)" ::: "memory");
      __builtin_amdgcn_sched_barrier(0);
      acc0 = __builtin_amdgcn_mfma_f32_16x16x32_bf16(a2, bw, acc0, 0, 0, 0);
    }
  }

  // epilogue: D[m=slot][c] -> af bf16 at (b*4+p)*704 + y*64 + c
  {
    const int c = cW;
    const int g = q;
    const float cb = conv_b[c];
    #pragma unroll
    for (int rr = 0; rr < 4; rr++) {
      if (mhalf == 0) {
        int m0 = g * 4 + rr;
        int p = m0 / FH, y = m0 - p * FH;
        float v = (sh_pos[m0] >= 0) ? (acc0[rr] + cb) : 0.0f;
        af[(size_t)(b * NPROP + p) * FDIM + y * 64 + c] = f2bf(v);
        int m1 = 16 + g * 4 + rr;
        p = m1 / FH; y = m1 - p * FH;
        v = (sh_pos[m1] >= 0) ? (acc1[rr] + cb) : 0.0f;
        af[(size_t)(b * NPROP + p) * FDIM + y * 64 + c] = f2bf(v);
      } else {
        int m2 = 32 + g * 4 + rr;
        if (m2 < 44) {
          int p = m2 / FH, y = m2 - p * FH;
          float v = (sh_pos[m2] >= 0) ? (acc0[rr] + cb) : 0.0f;
          af[(size_t)(b * NPROP + p) * FDIM + y * 64 + c] = f2bf(v);
        }
      }
    }
  }
}

// ---------------- Kernel 2: head GEMM (MFMA) + attention + assembly ------
__global__ __launch_bounds__(256) void k_head(
    const unsigned short* __restrict__ af, const float* __restrict__ xs,
    const unsigned short* __restrict__ Wc,
    const float* __restrict__ att_b, const float* __restrict__ cls_b,
    const float* __restrict__ reg_b, float* __restrict__ out)
{
  __shared__ __align__(16) unsigned short A_s[16 * 712];      // stride 712 bf16
  __shared__ __align__(16) unsigned short W_s[2][MROWS * 40]; // [n][k] stride 40
  __shared__ float Ys[16 * 161];
  __shared__ float Am[16][4];

  const int bg = blockIdx.x;
  const int t = threadIdx.x;
  const int l = t & 63;
  const int wid = t >> 6;

  {
    const unsigned* src = (const unsigned*)af + (size_t)bg * 16 * 352;
    for (int i = t; i < 16 * 352; i += 256) {
      int r = i / 352, ci = i - r * 352;
      ((unsigned*)A_s)[r * 356 + ci] = src[i];
    }
  }
  {
    #pragma unroll
    for (int e = t; e < 640; e += 256) {
      int n = e >> 2, jj = e & 3;
      uint4 ld = *(const uint4*)(Wc + n * FDIM + jj * 8);
      *(uint4*)(&W_s[0][n * 40 + jj * 8]) = ld;
    }
  }
  __syncthreads();

  f32x4 acc[3];
  acc[0] = (f32x4){0.f,0.f,0.f,0.f}; acc[1] = acc[0]; acc[2] = acc[0];

  for (int step = 0; step < 22; ++step) {
    int cur = step & 1;
    uint4 r0, r1, r2;
    bool h2 = (t + 512) < 640;
    if (step < 21) {
      int k0 = (step + 1) * 32;
      { int e = t;       int n = e >> 2, jj = e & 3; r0 = *(const uint4*)(Wc + n * FDIM + k0 + jj * 8); }
      { int e = t + 256; int n = e >> 2, jj = e & 3; r1 = *(const uint4*)(Wc + n * FDIM + k0 + jj * 8); }
      if (h2) { int e = t + 512; int n = e >> 2, jj = e & 3; r2 = *(const uint4*)(Wc + n * FDIM + k0 + jj * 8); }
    }
    bf16x8 a = *(const bf16x8*)(A_s + (l & 15) * 712 + step * 32 + (l >> 4) * 8);
    #pragma unroll
    for (int j = 0; j < 3; j++) {
      int ntl = wid + 4 * j;
      if (ntl < 10) {
        bf16x8 bb = *(const bf16x8*)(&W_s[cur][(ntl * 16 + (l & 15)) * 40 + (l >> 4) * 8]);
        acc[j] = __builtin_amdgcn_mfma_f32_16x16x32_bf16(a, bb, acc[j], 0, 0, 0);
      }
    }
    if (step < 21) {
      { int e = t;       int n = e >> 2, jj = e & 3; *(uint4*)(&W_s[cur ^ 1][n * 40 + jj * 8]) = r0; }
      { int e = t + 256; int n = e >> 2, jj = e & 3; *(uint4*)(&W_s[cur ^ 1][n * 40 + jj * 8]) = r1; }
      if (h2) { int e = t + 512; int n = e >> 2, jj = e & 3; *(uint4*)(&W_s[cur ^ 1][n * 40 + jj * 8]) = r2; }
    }
    __syncthreads();
  }

  #pragma unroll
  for (int j = 0; j < 3; j++) {
    int ntl = wid + 4 * j;
    if (ntl < 10) {
      #pragma unroll
      for (int r = 0; r < 4; r++)
        Ys[((l >> 4) * 4 + r) * 161 + ntl * 16 + (l & 15)] = acc[j][r];
    }
  }
  __syncthreads();

  if (t < 16) {
    float s0 = Ys[t * 161 + 150] + att_b[0];
    float s1 = Ys[t * 161 + 151] + att_b[1];
    float s2 = Ys[t * 161 + 152] + att_b[2];
    float mx = fmaxf(s0, fmaxf(s1, s2));
    float e0 = expf(s0 - mx), e1 = expf(s1 - mx), e2 = expf(s2 - mx);
    float inv = 1.0f / (e0 + e1 + e2);
    float aa[3] = {e0 * inv, e1 * inv, e2 * inv};
    int p = t & 3;
    #pragma unroll
    for (int qq = 0; qq < NPROP; qq++)
      Am[t][qq] = (qq == p) ? 0.0f : aa[(qq < p) ? qq : qq - 1];
  }
  __syncthreads();

  for (int d = t; d < 16 * 75; d += 256) {
    int row = d / 75, o = d - row * 75;
    float v = Ys[row * 161 + 75 + o];
    int base = row & ~3;
    #pragma unroll
    for (int qq = 0; qq < NPROP; qq++) v += Am[row][qq] * Ys[(base + qq) * 161 + o];
    v += (o < 2) ? cls_b[o] : reg_b[o - 2];
    int grow = bg * 16 + row;
    int col = (o < 2) ? o : o + 2;
    if (o >= 3) v += xs[grow * SFULL + (o - 3)];
    out[grow * 77 + col] = v;
  }
}

extern "C" void kernel_launch(void* const* d_in, const int* in_sizes, int n_in,
                              void* d_out, int out_size, void* d_ws, size_t ws_size,
                              hipStream_t stream) {
  const float* feat   = (const float*)d_in[0];
  const float* rpn    = (const float*)d_in[1];
  const float* conv_w = (const float*)d_in[2];
  const float* conv_b = (const float*)d_in[3];
  const float* att_w  = (const float*)d_in[4];
  const float* att_b  = (const float*)d_in[5];
  const float* cls_w  = (const float*)d_in[6];
  const float* cls_b  = (const float*)d_in[7];
  const float* reg_w  = (const float*)d_in[8];
  const float* reg_b  = (const float*)d_in[9];
  float* out = (float*)d_out;

  char* ws = (char*)d_ws;
  unsigned short* af  = (unsigned short*)ws;                        // 2,883,584 B
  float* xs           = (float*)(ws + 2883584);                     // 589,824 B
  unsigned short* Wc  = (unsigned short*)(ws + 2883584 + 589824);   // 225,280 B
  unsigned short* Wb2 = (unsigned short*)(ws + 2883584 + 589824 + 225280); // 65,536 B

  k_prep<<<224, 256, 0, stream>>>(cls_w, reg_w, att_w, conv_w, Wc, Wb2);
  k_gconv<<<512, 512, 0, stream>>>(feat, rpn, Wb2, conv_b, af, xs, out);
  k_head<<<128, 256, 0, stream>>>(af, xs, Wc, att_b, cls_b, reg_b, out);
}